// Round 8
// baseline (372.543 us; speedup 1.0000x reference)
//
#include <hip/hip_runtime.h>
#include <hip/hip_bf16.h>

// Bahdanau attention (R8):
//   q = dh @ Wq^T                                  (f32, tiny)
//   Wk -> bf16 (2 MB, L2-resident)
//   scores[b,s] = v . tanh(q[b] + Wk @ enc[b,s])   fused GEMM BM=128 x BN=512 x BK=32,
//     8 waves (2Mx4N, wave tile 64x128, acc[4][8]).  B: DIRECT global->register
//     fragments (no LDS, no ds_read for B -> lifts the 27% LDS-pipe ceiling),
//     double-buffered in regs, loads stay in flight across barriers (T4 via dataflow).
//     A: enc f32 read once -> in-reg cvt -> LDS (16 KB dbuf), 2-deep reg prefetch.
//     Loop manually 2x-unrolled: all buffer indices static.
//   attn = softmax(mask ? scores : -1e9)
//   ctx[b,e] = sum_s attn[b,s]*enc[b,s,e]          (memory-bound, f32)

#define NB 32
#define SS 2048
#define HD 1024
#define HE 1024
#define MM (NB * SS)   // 65536 rows
#define NT 32          // K-tiles = HE/32

typedef float f32x4 __attribute__((ext_vector_type(4)));
typedef short bf16x8 __attribute__((ext_vector_type(8)));
typedef short short4v __attribute__((ext_vector_type(4)));

static __device__ __forceinline__ short f2bf(float f) {
    union { __hip_bfloat16 h; short s; } u;
    u.h = __float2bfloat16(f);
    return u.s;
}

// ---------------- f32 -> bf16 conversion (Wk only, 1M elems) ----------------
__global__ __launch_bounds__(256) void cvt_bf16_kernel(const float* __restrict__ in,
                                                       short* __restrict__ out, int n8) {
    int i = blockIdx.x * 256 + threadIdx.x;
    const int stride = gridDim.x * 256;
    for (; i < n8; i += stride) {
        const f32x4 a = *(const f32x4*)(in + (long)i * 8);
        const f32x4 b = *(const f32x4*)(in + (long)i * 8 + 4);
        bf16x8 o;
        o[0] = f2bf(a[0]); o[1] = f2bf(a[1]); o[2] = f2bf(a[2]); o[3] = f2bf(a[3]);
        o[4] = f2bf(b[0]); o[5] = f2bf(b[1]); o[6] = f2bf(b[2]); o[7] = f2bf(b[3]);
        *(bf16x8*)(out + (long)i * 8) = o;
    }
}

// ---------------- q = dh @ Wq^T : one wave per output column d ----------------
__global__ __launch_bounds__(256) void qproj_kernel(const float* __restrict__ dh,
                                                    const float* __restrict__ Wq,
                                                    float* __restrict__ q) {
    const int wid  = threadIdx.x >> 6;
    const int lane = threadIdx.x & 63;
    const int d    = blockIdx.x * 4 + wid;
    const float* wrow = Wq + (long)d * HD + lane * 16;
    f32x4 w0 = *(const f32x4*)(wrow + 0);
    f32x4 w1 = *(const f32x4*)(wrow + 4);
    f32x4 w2 = *(const f32x4*)(wrow + 8);
    f32x4 w3 = *(const f32x4*)(wrow + 12);
    for (int b = 0; b < NB; ++b) {
        const float* drow = dh + b * HD + lane * 16;
        f32x4 d0 = *(const f32x4*)(drow + 0);
        f32x4 d1 = *(const f32x4*)(drow + 4);
        f32x4 d2 = *(const f32x4*)(drow + 8);
        f32x4 d3 = *(const f32x4*)(drow + 12);
        f32x4 s4 = w0 * d0 + w1 * d1 + w2 * d2 + w3 * d3;
        float dot = s4[0] + s4[1] + s4[2] + s4[3];
        #pragma unroll
        for (int off = 32; off > 0; off >>= 1)
            dot += __shfl_xor(dot, off, 64);
        if (lane == 0) q[b * HD + d] = dot;
    }
}

// ---------------- fused score GEMM: 128 rows x 512 cols per block ----------------
__global__ __launch_bounds__(512, 2) void score_fused_kernel(const float* __restrict__ enc,
                                                             const short* __restrict__ wkb,
                                                             const float* __restrict__ qv,
                                                             const float* __restrict__ ven,
                                                             float* __restrict__ sp) {
    __shared__ __align__(16) short As[2][128 * 32];   // 2 x 8 KB (A only; B never in LDS)

    // XCD swizzle: (mstrip, nt=0/1) adjacent on one XCD -> A K-slices shared in XCD L2
    const int bid    = blockIdx.x;
    const int xcd    = bid & 7;
    const int slot   = bid >> 3;               // 0..127
    const int mstrip = xcd * 64 + (slot >> 1); // 0..511
    const int nt     = slot & 1;               // N half

    const int tid  = threadIdx.x;
    const int lane = tid & 63;
    const int wid  = tid >> 6;            // 0..7
    const int wr   = wid >> 2;            // 0..1  (M half)
    const int wc   = wid & 3;             // 0..3  (N quarter of the half)
    const long mbase = (long)mstrip * 128;
    const int  nbase = nt * 512;

    f32x4 acc[4][8];
    #pragma unroll
    for (int m = 0; m < 4; ++m)
        #pragma unroll
        for (int n = 0; n < 8; ++n)
            acc[m][n] = (f32x4){0.f, 0.f, 0.f, 0.f};

    // A staging: thread t -> rows t>>3 and t>>3+64, f32-col (t&7)*4 (one f32x4 each)
    const float* ap0 = enc + (mbase + (tid >> 3)) * (long)HE + (tid & 7) * 4;
    const float* ap1 = ap0 + 64 * (long)HE;
    const int aoff0 = (tid >> 3) * 32 + (tid & 7) * 4;   // shorts within As[buf]
    const int aoff1 = aoff0 + 64 * 32;

    const int frow  = lane & 15;
    const int khalf = (lane >> 4) * 8;    // k-offset in shorts (0,8,16,24)

    // B per-lane fragment base: col = nbase + wc*128 + n*16 + frow, k = kt*32 + khalf
    const short* bbase = wkb + (long)(nbase + wc * 128 + frow) * HE + khalf;

    #define BLOAD(dst, KT)                                                   \
        do {                                                                 \
            _Pragma("unroll")                                                \
            for (int n = 0; n < 8; ++n)                                      \
                dst[n] = *(const bf16x8*)(bbase + (long)n * 16 * HE + (KT) * 32); \
        } while (0)

    #define ACOMMIT(BUF, RA, RB)                                             \
        do {                                                                 \
            short4v v0_, v1_;                                                \
            v0_[0]=f2bf(RA[0]); v0_[1]=f2bf(RA[1]); v0_[2]=f2bf(RA[2]); v0_[3]=f2bf(RA[3]); \
            v1_[0]=f2bf(RB[0]); v1_[1]=f2bf(RB[1]); v1_[2]=f2bf(RB[2]); v1_[3]=f2bf(RB[3]); \
            *(short4v*)((short*)As[BUF] + aoff0) = v0_;                      \
            *(short4v*)((short*)As[BUF] + aoff1) = v1_;                      \
        } while (0)

    // PHASE(CUR,KT): compute tile KT from As[CUR] x BCUR; issue B(KT+1)->BNXT and
    // A(KT+2)->AF regs; commit AH (=A(KT+1), loaded one phase ago) into As[CUR^1].
    // Barrier waits lgkmcnt only: B/A global loads stay in flight across it (T4).
    #define PHASE(CUR, KT, BCUR, BNXT, AH0, AH1, AF0, AF1)                   \
        do {                                                                 \
            if ((KT) + 1 < NT) BLOAD(BNXT, (KT) + 1);                        \
            if ((KT) + 2 < NT) {                                             \
                AF0 = *(const f32x4*)(ap0 + ((KT) + 2) * 32);                \
                AF1 = *(const f32x4*)(ap1 + ((KT) + 2) * 32);                \
            }                                                                \
            bf16x8 af_[4];                                                   \
            _Pragma("unroll")                                                \
            for (int m = 0; m < 4; ++m)                                      \
                af_[m] = *(const bf16x8*)((const short*)As[CUR]              \
                           + (wr * 64 + m * 16 + frow) * 32 + khalf);        \
            _Pragma("unroll")                                                \
            for (int m = 0; m < 4; ++m)                                      \
                _Pragma("unroll")                                            \
                for (int n = 0; n < 8; ++n)                                  \
                    acc[m][n] = __builtin_amdgcn_mfma_f32_16x16x32_bf16(     \
                        af_[m], BCUR[n], acc[m][n], 0, 0, 0);                \
            if ((KT) + 1 < NT) {                                             \
                ACOMMIT((CUR) ^ 1, AH0, AH1);                                \
                asm volatile("s_waitcnt lgkmcnt(0)\n\ts_barrier" ::: "memory"); \
            }                                                                \
        } while (0)

    // ---- prologue ----
    bf16x8 bE[8], bO[8];
    f32x4 aE0, aE1, aO0, aO1;
    {
        f32x4 aP0 = *(const f32x4*)(ap0);
        f32x4 aP1 = *(const f32x4*)(ap1);
        ACOMMIT(0, aP0, aP1);            // tile 0 into As[0]
        BLOAD(bE, 0);                    // B frags tile 0
        aE0 = *(const f32x4*)(ap0 + 32); // A tile 1 (consumed bottom of phase 0)
        aE1 = *(const f32x4*)(ap1 + 32);
        __syncthreads();
    }

    for (int kt = 0; kt < NT; kt += 2) {
        PHASE(0, kt,     bE, bO, aE0, aE1, aO0, aO1);
        PHASE(1, kt + 1, bO, bE, aO0, aO1, aE0, aE1);
    }
    #undef PHASE
    #undef ACOMMIT
    #undef BLOAD

    // ---- epilogue: partial score = sum over this wave's 128 cols of v[c]*tanh(q[b,c]+k)
    // C/D layout: col = lane&15 (N), row = (lane>>4)*4 + reg (M)
    const int bb = (int)(mbase >> 11);
    float qq[8], vv[8];
    #pragma unroll
    for (int n = 0; n < 8; ++n) {
        const int c = nbase + wc * 128 + n * 16 + frow;
        qq[n] = qv[bb * HD + c];
        vv[n] = ven[c];
    }
    float p[4][4];
    #pragma unroll
    for (int m = 0; m < 4; ++m) {
        #pragma unroll
        for (int rg = 0; rg < 4; ++rg) {
            float s = 0.f;
            #pragma unroll
            for (int n = 0; n < 8; ++n) {
                const float x = acc[m][n][rg] + qq[n];
                const float e = __expf(2.f * x);
                const float t = 1.f - 2.f * __builtin_amdgcn_rcpf(e + 1.f);
                s += vv[n] * t;
            }
            #pragma unroll
            for (int msk = 1; msk <= 8; msk <<= 1)
                s += __shfl_xor(s, msk, 64);   // reduce over 16-lane col group
            p[m][rg] = s;
        }
    }
    if ((lane & 15) == 0) {
        const int g = lane >> 4;
        float* dst = sp + (long)(nt * 4 + wc) * MM;   // 8 deterministic partial slots
        #pragma unroll
        for (int m = 0; m < 4; ++m)
            #pragma unroll
            for (int rg = 0; rg < 4; ++rg)
                dst[mbase + wr * 64 + m * 16 + g * 4 + rg] = p[m][rg];
    }
}

// ---------------- mask + softmax over S per batch ----------------
__global__ __launch_bounds__(256) void softmax_kernel(const float* __restrict__ sp,
                                                      const int* __restrict__ mask,
                                                      float* __restrict__ attn) {
    const int b = blockIdx.x;
    const int tid = threadIdx.x;
    const int lane = tid & 63;
    const int wid = tid >> 6;
    __shared__ float red[4];
    float sc[8];
    float mx = -3.0e38f;
    #pragma unroll
    for (int i = 0; i < 8; ++i) {
        const int s = tid + i * 256;
        float v = 0.f;
        #pragma unroll
        for (int k = 0; k < 8; ++k)
            v += sp[(long)k * MM + b * SS + s];
        if (mask[b * SS + s] == 0) v = -1e9f;
        sc[i] = v;
        mx = fmaxf(mx, v);
    }
    #pragma unroll
    for (int off = 32; off > 0; off >>= 1)
        mx = fmaxf(mx, __shfl_xor(mx, off, 64));
    if (lane == 0) red[wid] = mx;
    __syncthreads();
    mx = fmaxf(fmaxf(red[0], red[1]), fmaxf(red[2], red[3]));
    __syncthreads();
    float sum = 0.f;
    #pragma unroll
    for (int i = 0; i < 8; ++i) {
        const float e = __expf(sc[i] - mx);
        sc[i] = e;
        sum += e;
    }
    #pragma unroll
    for (int off = 32; off > 0; off >>= 1)
        sum += __shfl_xor(sum, off, 64);
    if (lane == 0) red[wid] = sum;
    __syncthreads();
    sum = red[0] + red[1] + red[2] + red[3];
    const float inv = 1.f / sum;
    #pragma unroll
    for (int i = 0; i < 8; ++i)
        attn[b * SS + tid + i * 256] = sc[i] * inv;
}

// ---------------- context: partial weighted sums over s-chunks (f32 enc) ----------------
__global__ __launch_bounds__(256) void ctx_partial_kernel(const float* __restrict__ enc,
                                                          const float* __restrict__ attn,
                                                          float* __restrict__ cp) {
    const int b = blockIdx.x >> 5;
    const int chunk = blockIdx.x & 31;
    const int tid = threadIdx.x;
    const float* ep = enc + ((long)b * SS + chunk * 64) * HE + tid * 4;
    const float* ap = attn + b * SS + chunk * 64;
    f32x4 acc = (f32x4){0.f, 0.f, 0.f, 0.f};
    #pragma unroll 4
    for (int s = 0; s < 64; ++s) {
        const float w = ap[s];
        const f32x4 v = *(const f32x4*)(ep + (long)s * HE);
        acc += w * v;
    }
    *(f32x4*)(cp + ((long)(b * 32 + chunk)) * HE + tid * 4) = acc;
}

__global__ __launch_bounds__(256) void ctx_reduce_kernel(const float* __restrict__ cp,
                                                         float* __restrict__ out) {
    const int o = blockIdx.x * 256 + threadIdx.x;
    const int b = o >> 10;
    const int e = o & 1023;
    float s = 0.f;
    #pragma unroll
    for (int c = 0; c < 32; ++c)
        s += cp[((long)(b * 32 + c)) * HE + e];
    out[o] = s;
}

extern "C" void kernel_launch(void* const* d_in, const int* in_sizes, int n_in,
                              void* d_out, int out_size, void* d_ws, size_t ws_size,
                              hipStream_t stream) {
    const float* dh   = (const float*)d_in[0];
    const float* enc  = (const float*)d_in[1];
    const int*   mask = (const int*)d_in[2];
    const float* Wq   = (const float*)d_in[3];
    const float* Wk   = (const float*)d_in[4];
    const float* Ve   = (const float*)d_in[5];

    float* out  = (float*)d_out;
    float* ctx  = out;
    float* attn = out + NB * HD;

    float* ws  = (float*)d_ws;
    float* wq_ = ws;                           // 32768 f
    float* sp  = ws + 32768;                   // 8 * 65536 f (2 MB)
    float* cp  = sp + 8 * (long)MM;            // 32*32*1024 f (4 MB)
    short* wkb = (short*)(cp + 32 * 32 * HE);  // 1M bf16 (2 MB)

    qproj_kernel<<<256, 256, 0, stream>>>(dh, Wq, wq_);
    cvt_bf16_kernel<<<512, 256, 0, stream>>>(Wk, wkb, HD * HE / 8);
    score_fused_kernel<<<1024, 512, 0, stream>>>(enc, wkb, wq_, Ve, sp);
    softmax_kernel<<<32, 256, 0, stream>>>(sp, mask, attn);
    ctx_partial_kernel<<<1024, 256, 0, stream>>>(enc, attn, cp);
    ctx_reduce_kernel<<<128, 256, 0, stream>>>(cp, ctx);
}

// Round 9
// 244.730 us; speedup vs baseline: 1.5223x; 1.5223x over previous
//
#include <hip/hip_runtime.h>
#include <hip/hip_bf16.h>

// Bahdanau attention (R9) = R6 skeleton + {A 2-deep reg prefetch, counted vmcnt(2)
// barrier, XOR slot-swizzled LDS (B: pre-swizzled global source + linear gload_lds
// dest; A: swizzled ds_write)}.
//   scores GEMM: BM=128 x BN=512 x BK=32, 512 thr / 8 waves (2Mx4N, wave 64x128,
//   acc[4][8] in AGPR), enc read once as f32 (in-reg cvt), B bf16 from L2.
//   swizzle: 16B slot q_store = q ^ (row&3) ^ ((row>>2)&3)  -> uniform 2-way banks.

#define NB 32
#define SS 2048
#define HD 1024
#define HE 1024
#define MM (NB * SS)   // 65536 rows
#define NT 32          // K-tiles = HE/32

typedef float f32x4 __attribute__((ext_vector_type(4)));
typedef short bf16x8 __attribute__((ext_vector_type(8)));
typedef short short4v __attribute__((ext_vector_type(4)));

static __device__ __forceinline__ short f2bf(float f) {
    union { __hip_bfloat16 h; short s; } u;
    u.h = __float2bfloat16(f);
    return u.s;
}

// async global->LDS, 16B per lane; LDS dest = wave-uniform base + lane*16.
static __device__ __forceinline__ void gload16(const void* g, const void* l) {
    __builtin_amdgcn_global_load_lds(
        (const __attribute__((address_space(1))) void*)(uintptr_t)(g),
        (__attribute__((address_space(3))) void*)(unsigned)(uintptr_t)(l),
        16, 0, 0);
}

// ---------------- f32 -> bf16 conversion (Wk only, 1M elems) ----------------
__global__ __launch_bounds__(256) void cvt_bf16_kernel(const float* __restrict__ in,
                                                       short* __restrict__ out, int n8) {
    int i = blockIdx.x * 256 + threadIdx.x;
    const int stride = gridDim.x * 256;
    for (; i < n8; i += stride) {
        const f32x4 a = *(const f32x4*)(in + (long)i * 8);
        const f32x4 b = *(const f32x4*)(in + (long)i * 8 + 4);
        bf16x8 o;
        o[0] = f2bf(a[0]); o[1] = f2bf(a[1]); o[2] = f2bf(a[2]); o[3] = f2bf(a[3]);
        o[4] = f2bf(b[0]); o[5] = f2bf(b[1]); o[6] = f2bf(b[2]); o[7] = f2bf(b[3]);
        *(bf16x8*)(out + (long)i * 8) = o;
    }
}

// ---------------- q = dh @ Wq^T : one wave per output column d ----------------
__global__ __launch_bounds__(256) void qproj_kernel(const float* __restrict__ dh,
                                                    const float* __restrict__ Wq,
                                                    float* __restrict__ q) {
    const int wid  = threadIdx.x >> 6;
    const int lane = threadIdx.x & 63;
    const int d    = blockIdx.x * 4 + wid;
    const float* wrow = Wq + (long)d * HD + lane * 16;
    f32x4 w0 = *(const f32x4*)(wrow + 0);
    f32x4 w1 = *(const f32x4*)(wrow + 4);
    f32x4 w2 = *(const f32x4*)(wrow + 8);
    f32x4 w3 = *(const f32x4*)(wrow + 12);
    for (int b = 0; b < NB; ++b) {
        const float* drow = dh + b * HD + lane * 16;
        f32x4 d0 = *(const f32x4*)(drow + 0);
        f32x4 d1 = *(const f32x4*)(drow + 4);
        f32x4 d2 = *(const f32x4*)(drow + 8);
        f32x4 d3 = *(const f32x4*)(drow + 12);
        f32x4 s4 = w0 * d0 + w1 * d1 + w2 * d2 + w3 * d3;
        float dot = s4[0] + s4[1] + s4[2] + s4[3];
        #pragma unroll
        for (int off = 32; off > 0; off >>= 1)
            dot += __shfl_xor(dot, off, 64);
        if (lane == 0) q[b * HD + d] = dot;
    }
}

// ---------------- fused score GEMM: 128 rows x 512 cols per block ----------------
__global__ __launch_bounds__(512, 2) void score_fused_kernel(const float* __restrict__ enc,
                                                             const short* __restrict__ wkb,
                                                             const float* __restrict__ qv,
                                                             const float* __restrict__ ven,
                                                             float* __restrict__ sp) {
    __shared__ __align__(16) short As[2][128 * 32];   // 2 x 8 KB
    __shared__ __align__(16) short Bs[2][512 * 32];   // 2 x 32 KB

    // XCD swizzle: (mstrip, nt=0/1) adjacent on one XCD -> A K-slices shared in XCD L2
    const int bid    = blockIdx.x;
    const int xcd    = bid & 7;
    const int slot   = bid >> 3;               // 0..127
    const int mstrip = xcd * 64 + (slot >> 1); // 0..511
    const int nt     = slot & 1;               // N half

    const int tid  = threadIdx.x;
    const int lane = tid & 63;
    const int wid  = tid >> 6;            // 0..7
    const int wr   = wid >> 2;            // 0..1  (M half)
    const int wc   = wid & 3;             // 0..3  (N quarter of the half)
    const long mbase = (long)mstrip * 128;
    const int  nbase = nt * 512;

    f32x4 acc[4][8];
    #pragma unroll
    for (int m = 0; m < 4; ++m)
        #pragma unroll
        for (int n = 0; n < 8; ++n)
            acc[m][n] = (f32x4){0.f, 0.f, 0.f, 0.f};

    // ---- A staging: thread t -> rows t>>3 and t>>3+64, f32-col (t&7)*4
    const int arow = tid >> 3;
    const float* ap0 = enc + (mbase + arow) * (long)HE + (tid & 7) * 4;
    const float* ap1 = ap0 + 64 * (long)HE;
    // swizzled ds_write: slot q=(tid&7)>>1, half h=tid&1; s(row)=(row&3)^((row>>2)&3)
    const int as_  = (arow & 3) ^ ((arow >> 2) & 3);
    const int awb  = (((tid & 7) >> 1) ^ as_) * 16 + (tid & 1) * 8;
    const int aw0  = arow * 64 + awb;            // bytes in As[buf]
    const int aw1  = (arow + 64) * 64 + awb;     // same swizzle (row+64: s unchanged)

    // ---- B staging: chunks c=j*512+tid -> row j*128+(tid>>2), dest slot tid&3 (linear).
    // source k pre-swizzled so logical slot = dest ^ s(row):
    const int bswz = ((tid & 3) ^ ((tid >> 2) & 3) ^ ((tid >> 4) & 3)) * 8;  // shorts
    const short* bp0 = wkb + (long)(nbase + (tid >> 2)) * HE + bswz;
    const short* bp1 = bp0 + 128 * (long)HE;     // j=1 (s(row) unchanged mod 128)
    const short* bp2 = bp1 + 128 * (long)HE;
    const short* bp3 = bp2 + 128 * (long)HE;
    const int bd0 = (0 * 512 + wid * 64) * 16;   // linear LDS byte dests (+ lane*16)
    const int bd1 = (1 * 512 + wid * 64) * 16;
    const int bd2 = (2 * 512 + wid * 64) * 16;
    const int bd3 = (3 * 512 + wid * 64) * 16;

    // ---- frag reads: row*64 + kby, kby = (slot ^ s(row))*16, s = f(frow) only
    const int frow = lane & 15;
    const int kby  = (((lane >> 4) ^ (frow & 3) ^ ((frow >> 2) & 3))) * 16;

    #define BSTAGE(BUF, KT)                                  \
        do {                                                 \
            const int ko_ = (KT) * 32;                       \
            gload16(bp0 + ko_, (char*)Bs[BUF] + bd0);        \
            gload16(bp1 + ko_, (char*)Bs[BUF] + bd1);        \
            gload16(bp2 + ko_, (char*)Bs[BUF] + bd2);        \
            gload16(bp3 + ko_, (char*)Bs[BUF] + bd3);        \
        } while (0)

    #define ACOMMIT(BUF, RA, RB)                                             \
        do {                                                                 \
            short4v v0_, v1_;                                                \
            v0_[0]=f2bf(RA[0]); v0_[1]=f2bf(RA[1]); v0_[2]=f2bf(RA[2]); v0_[3]=f2bf(RA[3]); \
            v1_[0]=f2bf(RB[0]); v1_[1]=f2bf(RB[1]); v1_[2]=f2bf(RB[2]); v1_[3]=f2bf(RB[3]); \
            *(short4v*)((char*)As[BUF] + aw0) = v0_;                         \
            *(short4v*)((char*)As[BUF] + aw1) = v1_;                         \
        } while (0)

    #define COMPUTE(CUR)                                                     \
        do {                                                                 \
            bf16x8 af_[4], bf_[8];                                           \
            _Pragma("unroll")                                                \
            for (int m = 0; m < 4; ++m)                                      \
                af_[m] = *(const bf16x8*)((const char*)As[CUR]               \
                           + (wr * 64 + m * 16 + frow) * 64 + kby);          \
            _Pragma("unroll")                                                \
            for (int n = 0; n < 8; ++n)                                      \
                bf_[n] = *(const bf16x8*)((const char*)Bs[CUR]               \
                           + (wc * 128 + n * 16 + frow) * 64 + kby);         \
            _Pragma("unroll")                                                \
            for (int m = 0; m < 4; ++m)                                      \
                _Pragma("unroll")                                            \
                for (int n = 0; n < 8; ++n)                                  \
                    acc[m][n] = __builtin_amdgcn_mfma_f32_16x16x32_bf16(     \
                        af_[m], bf_[n], acc[m][n], 0, 0, 0);                 \
        } while (0)

    // steady phase KT (KT+2 < NT): stage B(KT+1), issue A(KT+2), compute KT,
    // commit A(KT+1) (regs loaded last phase -> cvt's implicit wait vmcnt<=6
    // only forces B(KT+1)'s *older* A; bottom vmcnt(2) leaves A(KT+2) in flight.
    #define PHASE_S(CUR, KT, AH0, AH1, AF0, AF1)                             \
        do {                                                                 \
            BSTAGE((CUR) ^ 1, (KT) + 1);                                     \
            AF0 = *(const f32x4*)(ap0 + ((KT) + 2) * 32);                    \
            AF1 = *(const f32x4*)(ap1 + ((KT) + 2) * 32);                    \
            COMPUTE(CUR);                                                    \
            ACOMMIT((CUR) ^ 1, AH0, AH1);                                    \
            asm volatile("s_waitcnt vmcnt(2) lgkmcnt(0)\n\ts_barrier" ::: "memory"); \
        } while (0)

    // ---- prologue: B(0)+A(0) staged, A(1) in flight ----
    bf16x8 dummy_unused;
    f32x4 aE0, aE1, aO0, aO1;
    {
        BSTAGE(0, 0);
        f32x4 p0 = *(const f32x4*)(ap0);
        f32x4 p1 = *(const f32x4*)(ap1);
        ACOMMIT(0, p0, p1);                       // waits p0/p1 -> drains B(0) too
        aE0 = *(const f32x4*)(ap0 + 32);
        aE1 = *(const f32x4*)(ap1 + 32);
        asm volatile("s_waitcnt lgkmcnt(0)\n\ts_barrier" ::: "memory");
    }

    // ---- steady: phases 0..27 ----
    for (int kt = 0; kt < NT - 4; kt += 2) {
        PHASE_S(0, kt,     aE0, aE1, aO0, aO1);
        PHASE_S(1, kt + 1, aO0, aO1, aE0, aE1);
    }
    // ---- peel 28..31 ----
    PHASE_S(0, NT - 4, aE0, aE1, aO0, aO1);       // kt=28: loads A(30)
    PHASE_S(1, NT - 3, aO0, aO1, aE0, aE1);       // kt=29: loads A(31)
    {   // kt=30: stage B(31), compute, commit A(31); no A-load -> full drain
        BSTAGE(1, NT - 1);
        COMPUTE(0);
        ACOMMIT(1, aE0, aE1);
        asm volatile("s_waitcnt vmcnt(0) lgkmcnt(0)\n\ts_barrier" ::: "memory");
    }
    COMPUTE(1);                                   // kt=31
    #undef PHASE_S
    #undef COMPUTE
    #undef ACOMMIT
    #undef BSTAGE

    // ---- epilogue: partial score = sum over this wave's 128 cols of v[c]*tanh(q[b,c]+k)
    // C/D layout: col = lane&15 (N), row = (lane>>4)*4 + reg (M)
    const int bb = (int)(mbase >> 11);
    float qq[8], vv[8];
    #pragma unroll
    for (int n = 0; n < 8; ++n) {
        const int c = nbase + wc * 128 + n * 16 + frow;
        qq[n] = qv[bb * HD + c];
        vv[n] = ven[c];
    }
    float p[4][4];
    #pragma unroll
    for (int m = 0; m < 4; ++m) {
        #pragma unroll
        for (int rg = 0; rg < 4; ++rg) {
            float s = 0.f;
            #pragma unroll
            for (int n = 0; n < 8; ++n) {
                const float x = acc[m][n][rg] + qq[n];
                const float e = __expf(2.f * x);
                const float t = 1.f - 2.f * __builtin_amdgcn_rcpf(e + 1.f);
                s += vv[n] * t;
            }
            #pragma unroll
            for (int msk = 1; msk <= 8; msk <<= 1)
                s += __shfl_xor(s, msk, 64);   // reduce over 16-lane col group
            p[m][rg] = s;
        }
    }
    if ((lane & 15) == 0) {
        const int g = lane >> 4;
        float* dst = sp + (long)(nt * 4 + wc) * MM;   // 8 deterministic partial slots
        #pragma unroll
        for (int m = 0; m < 4; ++m)
            #pragma unroll
            for (int rg = 0; rg < 4; ++rg)
                dst[mbase + wr * 64 + m * 16 + g * 4 + rg] = p[m][rg];
    }
}

// ---------------- mask + softmax over S per batch ----------------
__global__ __launch_bounds__(256) void softmax_kernel(const float* __restrict__ sp,
                                                      const int* __restrict__ mask,
                                                      float* __restrict__ attn) {
    const int b = blockIdx.x;
    const int tid = threadIdx.x;
    const int lane = tid & 63;
    const int wid = tid >> 6;
    __shared__ float red[4];
    float sc[8];
    float mx = -3.0e38f;
    #pragma unroll
    for (int i = 0; i < 8; ++i) {
        const int s = tid + i * 256;
        float v = 0.f;
        #pragma unroll
        for (int k = 0; k < 8; ++k)
            v += sp[(long)k * MM + b * SS + s];
        if (mask[b * SS + s] == 0) v = -1e9f;
        sc[i] = v;
        mx = fmaxf(mx, v);
    }
    #pragma unroll
    for (int off = 32; off > 0; off >>= 1)
        mx = fmaxf(mx, __shfl_xor(mx, off, 64));
    if (lane == 0) red[wid] = mx;
    __syncthreads();
    mx = fmaxf(fmaxf(red[0], red[1]), fmaxf(red[2], red[3]));
    __syncthreads();
    float sum = 0.f;
    #pragma unroll
    for (int i = 0; i < 8; ++i) {
        const float e = __expf(sc[i] - mx);
        sc[i] = e;
        sum += e;
    }
    #pragma unroll
    for (int off = 32; off > 0; off >>= 1)
        sum += __shfl_xor(sum, off, 64);
    if (lane == 0) red[wid] = sum;
    __syncthreads();
    sum = red[0] + red[1] + red[2] + red[3];
    const float inv = 1.f / sum;
    #pragma unroll
    for (int i = 0; i < 8; ++i)
        attn[b * SS + tid + i * 256] = sc[i] * inv;
}

// ---------------- context: partial weighted sums over s-chunks (f32 enc) ----------------
__global__ __launch_bounds__(256) void ctx_partial_kernel(const float* __restrict__ enc,
                                                          const float* __restrict__ attn,
                                                          float* __restrict__ cp) {
    const int b = blockIdx.x >> 5;
    const int chunk = blockIdx.x & 31;
    const int tid = threadIdx.x;
    const float* ep = enc + ((long)b * SS + chunk * 64) * HE + tid * 4;
    const float* ap = attn + b * SS + chunk * 64;
    f32x4 acc = (f32x4){0.f, 0.f, 0.f, 0.f};
    #pragma unroll 4
    for (int s = 0; s < 64; ++s) {
        const float w = ap[s];
        const f32x4 v = *(const f32x4*)(ep + (long)s * HE);
        acc += w * v;
    }
    *(f32x4*)(cp + ((long)(b * 32 + chunk)) * HE + tid * 4) = acc;
}

__global__ __launch_bounds__(256) void ctx_reduce_kernel(const float* __restrict__ cp,
                                                         float* __restrict__ out) {
    const int o = blockIdx.x * 256 + threadIdx.x;
    const int b = o >> 10;
    const int e = o & 1023;
    float s = 0.f;
    #pragma unroll
    for (int c = 0; c < 32; ++c)
        s += cp[((long)(b * 32 + c)) * HE + e];
    out[o] = s;
}

extern "C" void kernel_launch(void* const* d_in, const int* in_sizes, int n_in,
                              void* d_out, int out_size, void* d_ws, size_t ws_size,
                              hipStream_t stream) {
    const float* dh   = (const float*)d_in[0];
    const float* enc  = (const float*)d_in[1];
    const int*   mask = (const int*)d_in[2];
    const float* Wq   = (const float*)d_in[3];
    const float* Wk   = (const float*)d_in[4];
    const float* Ve   = (const float*)d_in[5];

    float* out  = (float*)d_out;
    float* ctx  = out;
    float* attn = out + NB * HD;

    float* ws  = (float*)d_ws;
    float* wq_ = ws;                           // 32768 f
    float* sp  = ws + 32768;                   // 8 * 65536 f (2 MB)
    float* cp  = sp + 8 * (long)MM;            // 32*32*1024 f (4 MB)
    short* wkb = (short*)(cp + 32 * 32 * HE);  // 1M bf16 (2 MB)

    qproj_kernel<<<256, 256, 0, stream>>>(dh, Wq, wq_);
    cvt_bf16_kernel<<<512, 256, 0, stream>>>(Wk, wkb, HD * HE / 8);
    score_fused_kernel<<<1024, 512, 0, stream>>>(enc, wkb, wq_, Ve, sp);
    softmax_kernel<<<32, 256, 0, stream>>>(sp, mask, attn);
    ctx_partial_kernel<<<1024, 256, 0, stream>>>(enc, attn, cp);
    ctx_reduce_kernel<<<128, 256, 0, stream>>>(cp, ctx);
}